// Round 2
// baseline (42389.688 us; speedup 1.0000x reference)
//
#include <hip/hip_runtime.h>
#include <stdint.h>

// RevGRU encoder, MI355X. Structure:
//   prep   : build transposed split-bf16 x-projection weights (per layer) + bias; zero flags/saved[0]
//   gemmx  : X[t*64+b][1536] = x @ [Wz1x|Wg1x|Wz2x|Wg2x] + bias   (split-bf16 MFMA, 3 mfma/term)
//   scan   : 64 persistent WGs = 4 batch domains x 16 column groups; 4 flag barriers per layer-step;
//            recurrent weights live in registers as MFMA B-frags (split-bf16, 6 mfma on z, 3 on g);
//            exact int32 fixed-point h updates; broadcasts through global (L2/L3).
// R2 change: ALL scratch in static __device__ globals (R1 used ~272 MB of d_ws without
// checking ws_size -> likely OOB -> GPU abort). d_ws is now unused.

typedef __attribute__((ext_vector_type(8))) short short8;
typedef __attribute__((ext_vector_type(4))) float floatx4;

#define MFMA16(a,b,c) __builtin_amdgcn_mfma_f32_16x16x32_bf16((a),(b),(c),0,0,0)

__device__ __forceinline__ short bf16_rne(float f) {
  uint32_t u = __float_as_uint(f);
  u += 0x7FFFu + ((u >> 16) & 1u);
  return (short)(u >> 16);
}
__device__ __forceinline__ float bf16f(short s) {
  return __uint_as_float(((uint32_t)(uint16_t)s) << 16);
}

#define SCALE_F 8388608.0f
#define INV_S   (1.0f/8388608.0f)

// ---- static device scratch (persist across calls; fully rewritten each call) ----
__device__ float g_X[50331648];      // 32768 x 1536  (201 MB)
__device__ float g_hs0f[16777216];   // 32768 x 512   (67 MB)
__device__ short g_WT_hi[786432];    // 1536 x 512
__device__ short g_WT_lo[786432];
__device__ float g_bias[1536];
__device__ int   g_bc[98304];        // 4 domains x 6 x 4096
__device__ int   g_flags[4096];

// ------------------------------------------------------------------
__global__ void prep_kernel(const float* __restrict__ Wz1, const float* __restrict__ bz1,
                            const float* __restrict__ Wg1, const float* __restrict__ bg1,
                            const float* __restrict__ Wz2, const float* __restrict__ bz2,
                            const float* __restrict__ Wg2, const float* __restrict__ bg2,
                            int layer, int* __restrict__ d_out, int zero_extra) {
  int idx = blockIdx.x * 256 + threadIdx.x;   // grid covers 512*1536 exactly
  int k = idx / 1536;
  int c = idx - k * 1536;
  const float* W; const float* bb; int cc; int ncols;
  if (c < 512)       { W = Wz1; bb = bz1; cc = c;        ncols = 512; }
  else if (c < 768)  { W = Wg1; bb = bg1; cc = c - 512;  ncols = 256; }
  else if (c < 1280) { W = Wz2; bb = bz2; cc = c - 768;  ncols = 512; }
  else               { W = Wg2; bb = bg2; cc = c - 1280; ncols = 256; }
  float wv = W[(size_t)layer * 768 * ncols + (size_t)k * ncols + cc];
  short hi = bf16_rne(wv);
  short lo = bf16_rne(wv - bf16f(hi));
  g_WT_hi[(size_t)c * 512 + k] = hi;   // transposed [col][k] for frag-friendly staging
  g_WT_lo[(size_t)c * 512 + k] = lo;
  if (k == 0) g_bias[c] = bb[layer * ncols + cc];
  if (zero_extra) {
    if (idx < 4096) g_flags[idx] = 0;
    if (idx < 6400) d_out[65536 + idx] = 0;   // saved[0] = h0 = zeros
  }
}

// ------------------------------------------------------------------
__global__ __launch_bounds__(256)
void gemmx_kernel(const int* __restrict__ seq, const float* __restrict__ emb, int use_seq) {
  __shared__ float At[128][36];
  __shared__ short Bhi[128][40];
  __shared__ short Blo[128][40];
  __shared__ int toks[128];
  int tid = threadIdx.x;
  int r0 = blockIdx.x * 128;
  int c0 = blockIdx.y * 128;
  if (use_seq && tid < 128) toks[tid] = seq[r0 + tid];
  int lane = tid & 63;
  int wid = tid >> 6;
  int wm = wid & 1, wn = wid >> 1;
  int lm = lane & 15, lq = lane >> 4;
  floatx4 zero4 = {0.f, 0.f, 0.f, 0.f};
  floatx4 acc[4][4];
#pragma unroll
  for (int a = 0; a < 4; ++a)
#pragma unroll
    for (int b = 0; b < 4; ++b) acc[a][b] = zero4;
  __syncthreads();
  int am = tid >> 1;
  int ah = (tid & 1) * 16;
  const float* arow;
  if (use_seq) arow = emb + (size_t)toks[am] * 512;
  else         arow = g_hs0f + (size_t)(r0 + am) * 512;
  const short* bh_base = g_WT_hi + (size_t)(c0 + am) * 512;
  const short* bl_base = g_WT_lo + (size_t)(c0 + am) * 512;
  for (int kb = 0; kb < 16; ++kb) {
    int k0 = kb * 32 + ah;
    float4 a0 = *(const float4*)(arow + k0);
    float4 a1 = *(const float4*)(arow + k0 + 4);
    float4 a2 = *(const float4*)(arow + k0 + 8);
    float4 a3 = *(const float4*)(arow + k0 + 12);
    short4 b0 = *(const short4*)(bh_base + k0);
    short4 b1 = *(const short4*)(bh_base + k0 + 4);
    short4 b2 = *(const short4*)(bh_base + k0 + 8);
    short4 b3 = *(const short4*)(bh_base + k0 + 12);
    short4 l0 = *(const short4*)(bl_base + k0);
    short4 l1 = *(const short4*)(bl_base + k0 + 4);
    short4 l2 = *(const short4*)(bl_base + k0 + 8);
    short4 l3 = *(const short4*)(bl_base + k0 + 12);
    __syncthreads();
    *(float4*)&At[am][ah]      = a0;
    *(float4*)&At[am][ah + 4]  = a1;
    *(float4*)&At[am][ah + 8]  = a2;
    *(float4*)&At[am][ah + 12] = a3;
    *(short4*)&Bhi[am][ah]      = b0;
    *(short4*)&Bhi[am][ah + 4]  = b1;
    *(short4*)&Bhi[am][ah + 8]  = b2;
    *(short4*)&Bhi[am][ah + 12] = b3;
    *(short4*)&Blo[am][ah]      = l0;
    *(short4*)&Blo[am][ah + 4]  = l1;
    *(short4*)&Blo[am][ah + 8]  = l2;
    *(short4*)&Blo[am][ah + 12] = l3;
    __syncthreads();
    short8 afh[4], afl[4];
#pragma unroll
    for (int mt = 0; mt < 4; ++mt) {
      const float* ap = &At[wm*64 + mt*16 + lm][lq*8];
#pragma unroll
      for (int j = 0; j < 8; ++j) {
        float v = ap[j];
        short hi = bf16_rne(v);
        afh[mt][j] = hi;
        afl[mt][j] = bf16_rne(v - bf16f(hi));
      }
    }
#pragma unroll
    for (int nt = 0; nt < 4; ++nt) {
      short8 bfh = *(short8*)&Bhi[wn*64 + nt*16 + lm][lq*8];
      short8 bfl = *(short8*)&Blo[wn*64 + nt*16 + lm][lq*8];
#pragma unroll
      for (int mt = 0; mt < 4; ++mt) {
        acc[mt][nt] = MFMA16(afh[mt], bfh, acc[mt][nt]);
        acc[mt][nt] = MFMA16(afl[mt], bfh, acc[mt][nt]);
        acc[mt][nt] = MFMA16(afh[mt], bfl, acc[mt][nt]);
      }
    }
  }
#pragma unroll
  for (int nt = 0; nt < 4; ++nt) {
    int gc = c0 + wn*64 + nt*16 + lm;
    float bv = g_bias[gc];
#pragma unroll
    for (int mt = 0; mt < 4; ++mt) {
#pragma unroll
      for (int i = 0; i < 4; ++i) {
        int gr = r0 + wm*64 + mt*16 + lq*4 + i;
        g_X[(size_t)gr * 1536 + gc] = acc[mt][nt][i] + bv;
      }
    }
  }
}

// ------------------------------------------------------------------
__global__ __launch_bounds__(256)
void scan_kernel(const float* __restrict__ Wz1g, const float* __restrict__ Wg1g,
                 const float* __restrict__ Wz2g, const float* __restrict__ Wg2g,
                 const int* __restrict__ lengths, int* __restrict__ d_out, int layer) {
  __shared__ int h1i[16][260];
  __shared__ int h2i[16][260];
  __shared__ short phi[16][264];
  __shared__ short pmi[16][264];
  __shared__ short plo[16][264];
  __shared__ float redbuf[1280];
  __shared__ int lens[16];

  int tid = threadIdx.x;
  int wg = blockIdx.x;
  int dm = wg >> 4;     // batch domain 0..3 (rows 16*dm .. +16)
  int cg = wg & 15;     // column group 0..15
  int rb0 = dm * 16;
  int lane = tid & 63;
  int wv = tid >> 6;
  int lm = lane & 15, lq = lane >> 4;

  int* bcD = g_bc + dm * (6 * 4096);
  int*   bc_zq1 = bcD;
  float* bc_p1  = (float*)(bcD + 1 * 4096);
  int*   bc_h1  = bcD + 2 * 4096;
  int*   bc_zq2 = bcD + 3 * 4096;
  float* bc_p2  = (float*)(bcD + 4 * 4096);
  int*   bc_h2  = bcD + 5 * 4096;
  int* flagD = g_flags + (layer * 4 + dm) * 512;

  if (tid < 16) lens[tid] = lengths[rb0 + tid];
  for (int i = tid; i < 16 * 260; i += 256) { ((int*)h1i)[i] = 0; ((int*)h2i)[i] = 0; }

  // ---- preload recurrent-weight B-frags into registers (split-bf16) ----
  short8 wz1a[4], wz1b[4], wz1c[4], wz2a[4], wz2b[4], wz2c[4];
  short8 wg1a[2], wg1b[2], wg2a[2], wg2b[2];
  {
    int nt = wv & 1, kh = wv >> 1;
    int colz = cg * 32 + nt * 16 + lm;
    const float* W1 = Wz1g + (size_t)layer * 768 * 512 + (size_t)512 * 512 + colz;
    const float* W2 = Wz2g + (size_t)layer * 768 * 512 + (size_t)512 * 512 + colz;
#pragma unroll
    for (int ks = 0; ks < 4; ++ks) {
      int k0 = kh * 128 + ks * 32 + lq * 8;
      short8 t0, t1, t2, u0, u1, u2;
#pragma unroll
      for (int j = 0; j < 8; ++j) {
        float v = W1[(size_t)(k0 + j) * 512] * INV_S;       // pre-scale: A is raw int h
        short a0 = bf16_rne(v); float r1 = v - bf16f(a0);
        short a1 = bf16_rne(r1); float r2 = r1 - bf16f(a1);
        t0[j] = a0; t1[j] = a1; t2[j] = bf16_rne(r2);
        float v2 = W2[(size_t)(k0 + j) * 512] * INV_S;
        short d0 = bf16_rne(v2); float s1 = v2 - bf16f(d0);
        short d1 = bf16_rne(s1); float s2 = s1 - bf16f(d1);
        u0[j] = d0; u1[j] = d1; u2[j] = bf16_rne(s2);
      }
      wz1a[ks] = t0; wz1b[ks] = t1; wz1c[ks] = t2;
      wz2a[ks] = u0; wz2b[ks] = u1; wz2c[ks] = u2;
    }
    int colg = cg * 16 + lm;
    const float* G1 = Wg1g + (size_t)layer * 768 * 256 + (size_t)512 * 256 + colg;
    const float* G2 = Wg2g + (size_t)layer * 768 * 256 + (size_t)512 * 256 + colg;
#pragma unroll
    for (int ks = 0; ks < 2; ++ks) {
      int k0 = wv * 64 + ks * 32 + lq * 8;
      short8 t0, t1, u0, u1;
#pragma unroll
      for (int j = 0; j < 8; ++j) {
        float v = G1[(size_t)(k0 + j) * 256];
        short a0 = bf16_rne(v);
        t0[j] = a0; t1[j] = bf16_rne(v - bf16f(a0));
        float v2 = G2[(size_t)(k0 + j) * 256];
        short d0 = bf16_rne(v2);
        u0[j] = d0; u1[j] = bf16_rne(v2 - bf16f(d0));
      }
      wg1a[ks] = t0; wg1b[ks] = t1; wg2a[ks] = u0; wg2b[ks] = u1;
    }
  }
  __syncthreads();

  int xr = tid & 15, xc = tid >> 4;
  auto ldx = [&](int tt, float& za, float& zb, float& g1x, float& ya, float& yb, float& g2x) {
    const float* base = g_X + (size_t)(tt * 64 + rb0 + xr) * 1536;
    float2 v1 = *(const float2*)(base + cg * 32 + 2 * xc);
    za = v1.x; zb = v1.y;
    g1x = base[512 + cg * 16 + xc];
    float2 v2 = *(const float2*)(base + 768 + cg * 32 + 2 * xc);
    ya = v2.x; yb = v2.y;
    g2x = base[1280 + cg * 16 + xc];
  };
  float cz1a, cz1b, cg1x, cz2a, cz2b, cg2x;
  ldx(0, cz1a, cz1b, cg1x, cz2a, cz2b, cg2x);

  for (int t = 0; t < 512; ++t) {
    float nz1a, nz1b, ng1x, nz2a, nz2b, ng2x;
    int tn = (t + 1 < 512) ? t + 1 : t;
    ldx(tn, nz1a, nz1b, ng1x, nz2a, nz2b, ng2x);   // prefetch next step's X

    // ================= P1: z1 =================
    if (t > 0) {
      int rr = tid >> 4, ko = (tid & 15) << 4;
#pragma unroll
      for (int i = 0; i < 4; ++i)
        *(int4*)&h2i[rr][ko + 4 * i] = *(const int4*)(bc_h2 + rr * 256 + ko + 4 * i);
    }
    __syncthreads();
    {
      int rr = tid >> 4, ko = (tid & 15) << 4;
#pragma unroll
      for (int i = 0; i < 16; ++i) {
        float v = (float)h2i[rr][ko + i];
        short a0 = bf16_rne(v); float r1 = v - bf16f(a0);
        short a1 = bf16_rne(r1); float r2 = r1 - bf16f(a1);
        phi[rr][ko + i] = a0; pmi[rr][ko + i] = a1; plo[rr][ko + i] = bf16_rne(r2);
      }
    }
    __syncthreads();
    {
      int nt = wv & 1, kh = wv >> 1;
      floatx4 acc = {0.f, 0.f, 0.f, 0.f};
#pragma unroll
      for (int ks = 0; ks < 4; ++ks) {
        int k0 = kh * 128 + ks * 32 + lq * 8;
        short8 a0 = *(short8*)&phi[lm][k0];
        short8 a1 = *(short8*)&pmi[lm][k0];
        short8 a2 = *(short8*)&plo[lm][k0];
        acc = MFMA16(a0, wz1a[ks], acc);
        acc = MFMA16(a0, wz1b[ks], acc);
        acc = MFMA16(a1, wz1a[ks], acc);
        acc = MFMA16(a1, wz1b[ks], acc);
        acc = MFMA16(a0, wz1c[ks], acc);
        acc = MFMA16(a2, wz1a[ks], acc);
      }
#pragma unroll
      for (int i = 0; i < 4; ++i) redbuf[kh * 576 + (lq * 4 + i) * 36 + nt * 16 + lm] = acc[i];
    }
    __syncthreads();
    {
#pragma unroll
      for (int u = 0; u < 2; ++u) {
        int cc = 2 * xc + u;
        float pre = redbuf[xr * 36 + cc] + redbuf[576 + xr * 36 + cc] + (u ? cz1b : cz1a);
        float s = 1.0f / (1.0f + expf(-pre));
        int gcol = cg * 32 + cc;
        if (gcol < 256) {
          float q = floorf((0.875f * s + 0.125f) * 1024.0f);
          int qi = (int)q; qi = qi < 1 ? 1 : (qi > 1024 ? 1024 : qi);
          bc_zq1[xr * 256 + gcol] = qi;
        } else {
          int rc = gcol - 256;
          bc_p1[xr * 256 + rc] = s * ((float)h2i[xr][rc] * INV_S);
        }
      }
    }
    __threadfence(); __syncthreads();
    if (tid == 0) __hip_atomic_store(&flagD[cg * 32], 4 * t + 1, __ATOMIC_RELEASE, __HIP_MEMORY_SCOPE_AGENT);
    if (tid < 16) while (__hip_atomic_load(&flagD[tid * 32], __ATOMIC_ACQUIRE, __HIP_MEMORY_SCOPE_AGENT) < 4 * t + 1) __builtin_amdgcn_s_sleep(2);
    __syncthreads();

    // ================= P2: g1 + h1 update =================
    {
      int rr = tid >> 4, ko = (tid & 15) << 4;
#pragma unroll
      for (int i = 0; i < 16; ++i) {
        float v = bc_p1[rr * 256 + ko + i];
        short a0 = bf16_rne(v);
        phi[rr][ko + i] = a0; plo[rr][ko + i] = bf16_rne(v - bf16f(a0));
      }
    }
    __syncthreads();
    {
      floatx4 acc = {0.f, 0.f, 0.f, 0.f};
#pragma unroll
      for (int ks = 0; ks < 2; ++ks) {
        int k0 = wv * 64 + ks * 32 + lq * 8;
        short8 a0 = *(short8*)&phi[lm][k0];
        short8 a1 = *(short8*)&plo[lm][k0];
        acc = MFMA16(a0, wg1a[ks], acc);
        acc = MFMA16(a1, wg1a[ks], acc);
        acc = MFMA16(a0, wg1b[ks], acc);
      }
#pragma unroll
      for (int i = 0; i < 4; ++i) redbuf[wv * 320 + (lq * 4 + i) * 20 + lm] = acc[i];
    }
    __syncthreads();
    {
      float pre = redbuf[xr * 20 + xc] + redbuf[320 + xr * 20 + xc]
                + redbuf[640 + xr * 20 + xc] + redbuf[960 + xr * 20 + xc] + cg1x;
      float g = tanhf(pre);
      int gc = cg * 16 + xc;
      int q = bc_zq1[xr * 256 + gc];
      int hold = h1i[xr][gc];
      float zf = (float)q * (1.0f / 1024.0f);
      int ni = (int)rintf((1.0f - zf) * g * SCALE_F);
      int hnew = (hold >> 10) * q + (((hold & 1023) * q) >> 10) + ni;
      if (t >= lens[xr]) hnew = hold;
      h1i[xr][gc] = hnew;
      bc_h1[xr * 256 + gc] = hnew;
      if (layer == 0) g_hs0f[(size_t)(t * 64 + rb0 + xr) * 512 + gc] = (float)hnew * INV_S;
      else if (gc < 100) d_out[65536 + (t + 1) * 6400 + (rb0 + xr) * 100 + gc] = hnew;
      if (t == 511) d_out[layer * 32768 + (rb0 + xr) * 512 + gc] = hnew;
    }
    __threadfence(); __syncthreads();
    if (tid == 0) __hip_atomic_store(&flagD[cg * 32], 4 * t + 2, __ATOMIC_RELEASE, __HIP_MEMORY_SCOPE_AGENT);
    if (tid < 16) while (__hip_atomic_load(&flagD[tid * 32], __ATOMIC_ACQUIRE, __HIP_MEMORY_SCOPE_AGENT) < 4 * t + 2) __builtin_amdgcn_s_sleep(2);
    __syncthreads();

    // ================= P3: z2 =================
    {
      int rr = tid >> 4, ko = (tid & 15) << 4;
#pragma unroll
      for (int i = 0; i < 4; ++i)
        *(int4*)&h1i[rr][ko + 4 * i] = *(const int4*)(bc_h1 + rr * 256 + ko + 4 * i);
    }
    __syncthreads();
    {
      int rr = tid >> 4, ko = (tid & 15) << 4;
#pragma unroll
      for (int i = 0; i < 16; ++i) {
        float v = (float)h1i[rr][ko + i];
        short a0 = bf16_rne(v); float r1 = v - bf16f(a0);
        short a1 = bf16_rne(r1); float r2 = r1 - bf16f(a1);
        phi[rr][ko + i] = a0; pmi[rr][ko + i] = a1; plo[rr][ko + i] = bf16_rne(r2);
      }
    }
    __syncthreads();
    {
      int nt = wv & 1, kh = wv >> 1;
      floatx4 acc = {0.f, 0.f, 0.f, 0.f};
#pragma unroll
      for (int ks = 0; ks < 4; ++ks) {
        int k0 = kh * 128 + ks * 32 + lq * 8;
        short8 a0 = *(short8*)&phi[lm][k0];
        short8 a1 = *(short8*)&pmi[lm][k0];
        short8 a2 = *(short8*)&plo[lm][k0];
        acc = MFMA16(a0, wz2a[ks], acc);
        acc = MFMA16(a0, wz2b[ks], acc);
        acc = MFMA16(a1, wz2a[ks], acc);
        acc = MFMA16(a1, wz2b[ks], acc);
        acc = MFMA16(a0, wz2c[ks], acc);
        acc = MFMA16(a2, wz2a[ks], acc);
      }
#pragma unroll
      for (int i = 0; i < 4; ++i) redbuf[kh * 576 + (lq * 4 + i) * 36 + nt * 16 + lm] = acc[i];
    }
    __syncthreads();
    {
#pragma unroll
      for (int u = 0; u < 2; ++u) {
        int cc = 2 * xc + u;
        float pre = redbuf[xr * 36 + cc] + redbuf[576 + xr * 36 + cc] + (u ? cz2b : cz2a);
        float s = 1.0f / (1.0f + expf(-pre));
        int gcol = cg * 32 + cc;
        if (gcol < 256) {
          float q = floorf((0.875f * s + 0.125f) * 1024.0f);
          int qi = (int)q; qi = qi < 1 ? 1 : (qi > 1024 ? 1024 : qi);
          bc_zq2[xr * 256 + gcol] = qi;
        } else {
          int rc = gcol - 256;
          bc_p2[xr * 256 + rc] = s * ((float)h1i[xr][rc] * INV_S);
        }
      }
    }
    __threadfence(); __syncthreads();
    if (tid == 0) __hip_atomic_store(&flagD[cg * 32], 4 * t + 3, __ATOMIC_RELEASE, __HIP_MEMORY_SCOPE_AGENT);
    if (tid < 16) while (__hip_atomic_load(&flagD[tid * 32], __ATOMIC_ACQUIRE, __HIP_MEMORY_SCOPE_AGENT) < 4 * t + 3) __builtin_amdgcn_s_sleep(2);
    __syncthreads();

    // ================= P4: g2 + h2 update =================
    {
      int rr = tid >> 4, ko = (tid & 15) << 4;
#pragma unroll
      for (int i = 0; i < 16; ++i) {
        float v = bc_p2[rr * 256 + ko + i];
        short a0 = bf16_rne(v);
        phi[rr][ko + i] = a0; plo[rr][ko + i] = bf16_rne(v - bf16f(a0));
      }
    }
    __syncthreads();
    {
      floatx4 acc = {0.f, 0.f, 0.f, 0.f};
#pragma unroll
      for (int ks = 0; ks < 2; ++ks) {
        int k0 = wv * 64 + ks * 32 + lq * 8;
        short8 a0 = *(short8*)&phi[lm][k0];
        short8 a1 = *(short8*)&plo[lm][k0];
        acc = MFMA16(a0, wg2a[ks], acc);
        acc = MFMA16(a1, wg2a[ks], acc);
        acc = MFMA16(a0, wg2b[ks], acc);
      }
#pragma unroll
      for (int i = 0; i < 4; ++i) redbuf[wv * 320 + (lq * 4 + i) * 20 + lm] = acc[i];
    }
    __syncthreads();
    {
      float pre = redbuf[xr * 20 + xc] + redbuf[320 + xr * 20 + xc]
                + redbuf[640 + xr * 20 + xc] + redbuf[960 + xr * 20 + xc] + cg2x;
      float g = tanhf(pre);
      int gc = cg * 16 + xc;
      int q = bc_zq2[xr * 256 + gc];
      int hold = h2i[xr][gc];
      float zf = (float)q * (1.0f / 1024.0f);
      int ni = (int)rintf((1.0f - zf) * g * SCALE_F);
      int hnew = (hold >> 10) * q + (((hold & 1023) * q) >> 10) + ni;
      if (t >= lens[xr]) hnew = hold;
      h2i[xr][gc] = hnew;
      bc_h2[xr * 256 + gc] = hnew;
      if (layer == 0) g_hs0f[(size_t)(t * 64 + rb0 + xr) * 512 + 256 + gc] = (float)hnew * INV_S;
      if (t == 511) d_out[layer * 32768 + (rb0 + xr) * 512 + 256 + gc] = hnew;
    }
    __threadfence(); __syncthreads();
    if (tid == 0) __hip_atomic_store(&flagD[cg * 32], 4 * t + 4, __ATOMIC_RELEASE, __HIP_MEMORY_SCOPE_AGENT);
    if (tid < 16) while (__hip_atomic_load(&flagD[tid * 32], __ATOMIC_ACQUIRE, __HIP_MEMORY_SCOPE_AGENT) < 4 * t + 4) __builtin_amdgcn_s_sleep(2);
    __syncthreads();

    cz1a = nz1a; cz1b = nz1b; cg1x = ng1x; cz2a = nz2a; cz2b = nz2b; cg2x = ng2x;
  }
}

// ------------------------------------------------------------------
extern "C" void kernel_launch(void* const* d_in, const int* in_sizes, int n_in,
                              void* d_out, int out_size, void* d_ws, size_t ws_size,
                              hipStream_t stream) {
  const int*   seq     = (const int*)d_in[0];
  const int*   lengths = (const int*)d_in[1];
  const float* emb     = (const float*)d_in[2];
  const float* Wz1     = (const float*)d_in[3];
  const float* bz1     = (const float*)d_in[4];
  const float* Wg1     = (const float*)d_in[5];
  const float* bg1     = (const float*)d_in[6];
  const float* Wz2     = (const float*)d_in[7];
  const float* bz2     = (const float*)d_in[8];
  const float* Wg2     = (const float*)d_in[9];
  const float* bg2     = (const float*)d_in[10];
  int* out = (int*)d_out;
  (void)in_sizes; (void)n_in; (void)out_size; (void)d_ws; (void)ws_size;

  for (int layer = 0; layer < 2; ++layer) {
    prep_kernel<<<3072, 256, 0, stream>>>(Wz1, bz1, Wg1, bg1, Wz2, bz2, Wg2, bg2,
                                          layer, out, layer == 0 ? 1 : 0);
    gemmx_kernel<<<dim3(256, 12), 256, 0, stream>>>(seq, emb, layer == 0 ? 1 : 0);
    scan_kernel<<<64, 256, 0, stream>>>(Wz1, Wg1, Wz2, Wg2, lengths, out, layer);
  }
}

// Round 3
// 19742.990 us; speedup vs baseline: 2.1471x; 2.1471x over previous
//
#include <hip/hip_runtime.h>
#include <stdint.h>

// RevGRU encoder, MI355X.
//   prep   : build transposed split-bf16 x-projection weights (per layer) + bias; zero flags/saved[0]
//   gemmx  : X[t*64+b][1536] = x @ [Wz1x|Wg1x|Wz2x|Wg2x] + bias   (split-bf16 MFMA, 3 mfma/term)
//   scan   : 64 persistent WGs = 4 batch domains x 16 column groups; 4 flag barriers per layer-step.
// R3 change: cross-WG protocol uses RELAXED agent-scope atomics (per-access sc1 coherence)
// instead of ACQUIRE/RELEASE + __threadfence. R2's fences emitted bulk L2 wb/inv per phase
// (10.3us/phase, FETCH 921MB from invalidate-driven refetch). Ordering data->flag is via
// __syncthreads() which emits s_waitcnt vmcnt(0) before s_barrier.

typedef __attribute__((ext_vector_type(8))) short short8;
typedef __attribute__((ext_vector_type(4))) float floatx4;

#define MFMA16(a,b,c) __builtin_amdgcn_mfma_f32_16x16x32_bf16((a),(b),(c),0,0,0)

__device__ __forceinline__ short bf16_rne(float f) {
  uint32_t u = __float_as_uint(f);
  u += 0x7FFFu + ((u >> 16) & 1u);
  return (short)(u >> 16);
}
__device__ __forceinline__ float bf16f(short s) {
  return __uint_as_float(((uint32_t)(uint16_t)s) << 16);
}

__device__ __forceinline__ void st_ag(int* p, int v) {
  __hip_atomic_store(p, v, __ATOMIC_RELAXED, __HIP_MEMORY_SCOPE_AGENT);
}
__device__ __forceinline__ int ld_ag(const int* p) {
  return __hip_atomic_load(p, __ATOMIC_RELAXED, __HIP_MEMORY_SCOPE_AGENT);
}
__device__ __forceinline__ void stf_ag(float* p, float v) {
  __hip_atomic_store(p, v, __ATOMIC_RELAXED, __HIP_MEMORY_SCOPE_AGENT);
}
__device__ __forceinline__ float ldf_ag(const float* p) {
  return __hip_atomic_load(p, __ATOMIC_RELAXED, __HIP_MEMORY_SCOPE_AGENT);
}

#define SCALE_F 8388608.0f
#define INV_S   (1.0f/8388608.0f)

// ---- static device scratch (persist across calls; fully rewritten each call) ----
__device__ float g_X[50331648];      // 32768 x 1536  (201 MB)
__device__ float g_hs0f[16777216];   // 32768 x 512   (67 MB)
__device__ short g_WT_hi[786432];    // 1536 x 512
__device__ short g_WT_lo[786432];
__device__ float g_bias[1536];
__device__ int   g_bc[98304];        // 4 domains x 6 x 4096
__device__ int   g_flags[4096];

// ------------------------------------------------------------------
__global__ void prep_kernel(const float* __restrict__ Wz1, const float* __restrict__ bz1,
                            const float* __restrict__ Wg1, const float* __restrict__ bg1,
                            const float* __restrict__ Wz2, const float* __restrict__ bz2,
                            const float* __restrict__ Wg2, const float* __restrict__ bg2,
                            int layer, int* __restrict__ d_out, int zero_extra) {
  int idx = blockIdx.x * 256 + threadIdx.x;   // grid covers 512*1536 exactly
  int k = idx / 1536;
  int c = idx - k * 1536;
  const float* W; const float* bb; int cc; int ncols;
  if (c < 512)       { W = Wz1; bb = bz1; cc = c;        ncols = 512; }
  else if (c < 768)  { W = Wg1; bb = bg1; cc = c - 512;  ncols = 256; }
  else if (c < 1280) { W = Wz2; bb = bz2; cc = c - 768;  ncols = 512; }
  else               { W = Wg2; bb = bg2; cc = c - 1280; ncols = 256; }
  float wv = W[(size_t)layer * 768 * ncols + (size_t)k * ncols + cc];
  short hi = bf16_rne(wv);
  short lo = bf16_rne(wv - bf16f(hi));
  g_WT_hi[(size_t)c * 512 + k] = hi;   // transposed [col][k] for frag-friendly staging
  g_WT_lo[(size_t)c * 512 + k] = lo;
  if (k == 0) g_bias[c] = bb[layer * ncols + cc];
  if (zero_extra) {
    if (idx < 4096) st_ag(&g_flags[idx], 0);
    if (idx < 6400) d_out[65536 + idx] = 0;   // saved[0] = h0 = zeros
  }
}

// ------------------------------------------------------------------
__global__ __launch_bounds__(256)
void gemmx_kernel(const int* __restrict__ seq, const float* __restrict__ emb, int use_seq) {
  __shared__ float At[128][36];
  __shared__ short Bhi[128][40];
  __shared__ short Blo[128][40];
  __shared__ int toks[128];
  int tid = threadIdx.x;
  int r0 = blockIdx.x * 128;
  int c0 = blockIdx.y * 128;
  if (use_seq && tid < 128) toks[tid] = seq[r0 + tid];
  int lane = tid & 63;
  int wid = tid >> 6;
  int wm = wid & 1, wn = wid >> 1;
  int lm = lane & 15, lq = lane >> 4;
  floatx4 zero4 = {0.f, 0.f, 0.f, 0.f};
  floatx4 acc[4][4];
#pragma unroll
  for (int a = 0; a < 4; ++a)
#pragma unroll
    for (int b = 0; b < 4; ++b) acc[a][b] = zero4;
  __syncthreads();
  int am = tid >> 1;
  int ah = (tid & 1) * 16;
  const float* arow;
  if (use_seq) arow = emb + (size_t)toks[am] * 512;
  else         arow = g_hs0f + (size_t)(r0 + am) * 512;
  const short* bh_base = g_WT_hi + (size_t)(c0 + am) * 512;
  const short* bl_base = g_WT_lo + (size_t)(c0 + am) * 512;
  for (int kb = 0; kb < 16; ++kb) {
    int k0 = kb * 32 + ah;
    float4 a0 = *(const float4*)(arow + k0);
    float4 a1 = *(const float4*)(arow + k0 + 4);
    float4 a2 = *(const float4*)(arow + k0 + 8);
    float4 a3 = *(const float4*)(arow + k0 + 12);
    short4 b0 = *(const short4*)(bh_base + k0);
    short4 b1 = *(const short4*)(bh_base + k0 + 4);
    short4 b2 = *(const short4*)(bh_base + k0 + 8);
    short4 b3 = *(const short4*)(bh_base + k0 + 12);
    short4 l0 = *(const short4*)(bl_base + k0);
    short4 l1 = *(const short4*)(bl_base + k0 + 4);
    short4 l2 = *(const short4*)(bl_base + k0 + 8);
    short4 l3 = *(const short4*)(bl_base + k0 + 12);
    __syncthreads();
    *(float4*)&At[am][ah]      = a0;
    *(float4*)&At[am][ah + 4]  = a1;
    *(float4*)&At[am][ah + 8]  = a2;
    *(float4*)&At[am][ah + 12] = a3;
    *(short4*)&Bhi[am][ah]      = b0;
    *(short4*)&Bhi[am][ah + 4]  = b1;
    *(short4*)&Bhi[am][ah + 8]  = b2;
    *(short4*)&Bhi[am][ah + 12] = b3;
    *(short4*)&Blo[am][ah]      = l0;
    *(short4*)&Blo[am][ah + 4]  = l1;
    *(short4*)&Blo[am][ah + 8]  = l2;
    *(short4*)&Blo[am][ah + 12] = l3;
    __syncthreads();
    short8 afh[4], afl[4];
#pragma unroll
    for (int mt = 0; mt < 4; ++mt) {
      const float* ap = &At[wm*64 + mt*16 + lm][lq*8];
#pragma unroll
      for (int j = 0; j < 8; ++j) {
        float v = ap[j];
        short hi = bf16_rne(v);
        afh[mt][j] = hi;
        afl[mt][j] = bf16_rne(v - bf16f(hi));
      }
    }
#pragma unroll
    for (int nt = 0; nt < 4; ++nt) {
      short8 bfh = *(short8*)&Bhi[wn*64 + nt*16 + lm][lq*8];
      short8 bfl = *(short8*)&Blo[wn*64 + nt*16 + lm][lq*8];
#pragma unroll
      for (int mt = 0; mt < 4; ++mt) {
        acc[mt][nt] = MFMA16(afh[mt], bfh, acc[mt][nt]);
        acc[mt][nt] = MFMA16(afl[mt], bfh, acc[mt][nt]);
        acc[mt][nt] = MFMA16(afh[mt], bfl, acc[mt][nt]);
      }
    }
  }
#pragma unroll
  for (int nt = 0; nt < 4; ++nt) {
    int gc = c0 + wn*64 + nt*16 + lm;
    float bv = g_bias[gc];
#pragma unroll
    for (int mt = 0; mt < 4; ++mt) {
#pragma unroll
      for (int i = 0; i < 4; ++i) {
        int gr = r0 + wm*64 + mt*16 + lq*4 + i;
        g_X[(size_t)gr * 1536 + gc] = acc[mt][nt][i] + bv;
      }
    }
  }
}

// ------------------------------------------------------------------
__global__ __launch_bounds__(256)
void scan_kernel(const float* __restrict__ Wz1g, const float* __restrict__ Wg1g,
                 const float* __restrict__ Wz2g, const float* __restrict__ Wg2g,
                 const int* __restrict__ lengths, int* __restrict__ d_out, int layer) {
  __shared__ int h1i[16][260];
  __shared__ int h2i[16][260];
  __shared__ short phi[16][264];
  __shared__ short pmi[16][264];
  __shared__ short plo[16][264];
  __shared__ float redbuf[1280];
  __shared__ int lens[16];

  int tid = threadIdx.x;
  int wg = blockIdx.x;
  int dm = wg >> 4;     // batch domain 0..3 (rows 16*dm .. +16)
  int cg = wg & 15;     // column group 0..15
  int rb0 = dm * 16;
  int lane = tid & 63;
  int wv = tid >> 6;
  int lm = lane & 15, lq = lane >> 4;

  int* bcD = g_bc + dm * (6 * 4096);
  int*   bc_zq1 = bcD;
  float* bc_p1  = (float*)(bcD + 1 * 4096);
  int*   bc_h1  = bcD + 2 * 4096;
  int*   bc_zq2 = bcD + 3 * 4096;
  float* bc_p2  = (float*)(bcD + 4 * 4096);
  int*   bc_h2  = bcD + 5 * 4096;
  int* flagD = g_flags + (layer * 4 + dm) * 512;

  if (tid < 16) lens[tid] = lengths[rb0 + tid];
  for (int i = tid; i < 16 * 260; i += 256) { ((int*)h1i)[i] = 0; ((int*)h2i)[i] = 0; }

  // ---- preload recurrent-weight B-frags into registers (split-bf16) ----
  short8 wz1a[4], wz1b[4], wz1c[4], wz2a[4], wz2b[4], wz2c[4];
  short8 wg1a[2], wg1b[2], wg2a[2], wg2b[2];
  {
    int nt = wv & 1, kh = wv >> 1;
    int colz = cg * 32 + nt * 16 + lm;
    const float* W1 = Wz1g + (size_t)layer * 768 * 512 + (size_t)512 * 512 + colz;
    const float* W2 = Wz2g + (size_t)layer * 768 * 512 + (size_t)512 * 512 + colz;
#pragma unroll
    for (int ks = 0; ks < 4; ++ks) {
      int k0 = kh * 128 + ks * 32 + lq * 8;
      short8 t0, t1, t2, u0, u1, u2;
#pragma unroll
      for (int j = 0; j < 8; ++j) {
        float v = W1[(size_t)(k0 + j) * 512] * INV_S;       // pre-scale: A is raw int h
        short a0 = bf16_rne(v); float r1 = v - bf16f(a0);
        short a1 = bf16_rne(r1); float r2 = r1 - bf16f(a1);
        t0[j] = a0; t1[j] = a1; t2[j] = bf16_rne(r2);
        float v2 = W2[(size_t)(k0 + j) * 512] * INV_S;
        short d0 = bf16_rne(v2); float s1 = v2 - bf16f(d0);
        short d1 = bf16_rne(s1); float s2 = s1 - bf16f(d1);
        u0[j] = d0; u1[j] = d1; u2[j] = bf16_rne(s2);
      }
      wz1a[ks] = t0; wz1b[ks] = t1; wz1c[ks] = t2;
      wz2a[ks] = u0; wz2b[ks] = u1; wz2c[ks] = u2;
    }
    int colg = cg * 16 + lm;
    const float* G1 = Wg1g + (size_t)layer * 768 * 256 + (size_t)512 * 256 + colg;
    const float* G2 = Wg2g + (size_t)layer * 768 * 256 + (size_t)512 * 256 + colg;
#pragma unroll
    for (int ks = 0; ks < 2; ++ks) {
      int k0 = wv * 64 + ks * 32 + lq * 8;
      short8 t0, t1, u0, u1;
#pragma unroll
      for (int j = 0; j < 8; ++j) {
        float v = G1[(size_t)(k0 + j) * 256];
        short a0 = bf16_rne(v);
        t0[j] = a0; t1[j] = bf16_rne(v - bf16f(a0));
        float v2 = G2[(size_t)(k0 + j) * 256];
        short d0 = bf16_rne(v2);
        u0[j] = d0; u1[j] = bf16_rne(v2 - bf16f(d0));
      }
      wg1a[ks] = t0; wg1b[ks] = t1; wg2a[ks] = u0; wg2b[ks] = u1;
    }
  }
  __syncthreads();

  int xr = tid & 15, xc = tid >> 4;
  auto ldx = [&](int tt, float& za, float& zb, float& g1x, float& ya, float& yb, float& g2x) {
    const float* base = g_X + (size_t)(tt * 64 + rb0 + xr) * 1536;
    float2 v1 = *(const float2*)(base + cg * 32 + 2 * xc);
    za = v1.x; zb = v1.y;
    g1x = base[512 + cg * 16 + xc];
    float2 v2 = *(const float2*)(base + 768 + cg * 32 + 2 * xc);
    ya = v2.x; yb = v2.y;
    g2x = base[1280 + cg * 16 + xc];
  };
  float cz1a, cz1b, cg1x, cz2a, cz2b, cg2x;
  ldx(0, cz1a, cz1b, cg1x, cz2a, cz2b, cg2x);

  for (int t = 0; t < 512; ++t) {
    float nz1a, nz1b, ng1x, nz2a, nz2b, ng2x;
    int tn = (t + 1 < 512) ? t + 1 : t;
    ldx(tn, nz1a, nz1b, ng1x, nz2a, nz2b, ng2x);   // prefetch next step's X

    // ================= P1: z1 =================
    if (t > 0) {
      int rr = tid >> 4, ko = (tid & 15) << 4;
#pragma unroll
      for (int i = 0; i < 16; ++i)
        h2i[rr][ko + i] = ld_ag(bc_h2 + rr * 256 + ko + i);
    }
    __syncthreads();
    {
      int rr = tid >> 4, ko = (tid & 15) << 4;
#pragma unroll
      for (int i = 0; i < 16; ++i) {
        float v = (float)h2i[rr][ko + i];
        short a0 = bf16_rne(v); float r1 = v - bf16f(a0);
        short a1 = bf16_rne(r1); float r2 = r1 - bf16f(a1);
        phi[rr][ko + i] = a0; pmi[rr][ko + i] = a1; plo[rr][ko + i] = bf16_rne(r2);
      }
    }
    __syncthreads();
    {
      int nt = wv & 1, kh = wv >> 1;
      floatx4 acc = {0.f, 0.f, 0.f, 0.f};
#pragma unroll
      for (int ks = 0; ks < 4; ++ks) {
        int k0 = kh * 128 + ks * 32 + lq * 8;
        short8 a0 = *(short8*)&phi[lm][k0];
        short8 a1 = *(short8*)&pmi[lm][k0];
        short8 a2 = *(short8*)&plo[lm][k0];
        acc = MFMA16(a0, wz1a[ks], acc);
        acc = MFMA16(a0, wz1b[ks], acc);
        acc = MFMA16(a1, wz1a[ks], acc);
        acc = MFMA16(a1, wz1b[ks], acc);
        acc = MFMA16(a0, wz1c[ks], acc);
        acc = MFMA16(a2, wz1a[ks], acc);
      }
#pragma unroll
      for (int i = 0; i < 4; ++i) redbuf[kh * 576 + (lq * 4 + i) * 36 + nt * 16 + lm] = acc[i];
    }
    __syncthreads();
    {
#pragma unroll
      for (int u = 0; u < 2; ++u) {
        int cc = 2 * xc + u;
        float pre = redbuf[xr * 36 + cc] + redbuf[576 + xr * 36 + cc] + (u ? cz1b : cz1a);
        float s = 1.0f / (1.0f + expf(-pre));
        int gcol = cg * 32 + cc;
        if (gcol < 256) {
          float q = floorf((0.875f * s + 0.125f) * 1024.0f);
          int qi = (int)q; qi = qi < 1 ? 1 : (qi > 1024 ? 1024 : qi);
          st_ag(&bc_zq1[xr * 256 + gcol], qi);
        } else {
          int rc = gcol - 256;
          stf_ag(&bc_p1[xr * 256 + rc], s * ((float)h2i[xr][rc] * INV_S));
        }
      }
    }
    __syncthreads();   // emits s_waitcnt vmcnt(0): all sc1 data stores acked before flag
    if (tid == 0) st_ag(&flagD[cg * 32], 4 * t + 1);
    if (tid < 16) while (ld_ag(&flagD[tid * 32]) < 4 * t + 1) __builtin_amdgcn_s_sleep(2);
    __syncthreads();

    // ================= P2: g1 + h1 update =================
    {
      int rr = tid >> 4, ko = (tid & 15) << 4;
#pragma unroll
      for (int i = 0; i < 16; ++i) {
        float v = ldf_ag(&bc_p1[rr * 256 + ko + i]);
        short a0 = bf16_rne(v);
        phi[rr][ko + i] = a0; plo[rr][ko + i] = bf16_rne(v - bf16f(a0));
      }
    }
    __syncthreads();
    {
      floatx4 acc = {0.f, 0.f, 0.f, 0.f};
#pragma unroll
      for (int ks = 0; ks < 2; ++ks) {
        int k0 = wv * 64 + ks * 32 + lq * 8;
        short8 a0 = *(short8*)&phi[lm][k0];
        short8 a1 = *(short8*)&plo[lm][k0];
        acc = MFMA16(a0, wg1a[ks], acc);
        acc = MFMA16(a1, wg1a[ks], acc);
        acc = MFMA16(a0, wg1b[ks], acc);
      }
#pragma unroll
      for (int i = 0; i < 4; ++i) redbuf[wv * 320 + (lq * 4 + i) * 20 + lm] = acc[i];
    }
    __syncthreads();
    {
      float pre = redbuf[xr * 20 + xc] + redbuf[320 + xr * 20 + xc]
                + redbuf[640 + xr * 20 + xc] + redbuf[960 + xr * 20 + xc] + cg1x;
      float g = tanhf(pre);
      int gc = cg * 16 + xc;
      int q = ld_ag(&bc_zq1[xr * 256 + gc]);
      int hold = h1i[xr][gc];
      float zf = (float)q * (1.0f / 1024.0f);
      int ni = (int)rintf((1.0f - zf) * g * SCALE_F);
      int hnew = (hold >> 10) * q + (((hold & 1023) * q) >> 10) + ni;
      if (t >= lens[xr]) hnew = hold;
      h1i[xr][gc] = hnew;
      st_ag(&bc_h1[xr * 256 + gc], hnew);
      if (layer == 0) g_hs0f[(size_t)(t * 64 + rb0 + xr) * 512 + gc] = (float)hnew * INV_S;
      else if (gc < 100) d_out[65536 + (t + 1) * 6400 + (rb0 + xr) * 100 + gc] = hnew;
      if (t == 511) d_out[layer * 32768 + (rb0 + xr) * 512 + gc] = hnew;
    }
    __syncthreads();
    if (tid == 0) st_ag(&flagD[cg * 32], 4 * t + 2);
    if (tid < 16) while (ld_ag(&flagD[tid * 32]) < 4 * t + 2) __builtin_amdgcn_s_sleep(2);
    __syncthreads();

    // ================= P3: z2 =================
    {
      int rr = tid >> 4, ko = (tid & 15) << 4;
#pragma unroll
      for (int i = 0; i < 16; ++i)
        h1i[rr][ko + i] = ld_ag(bc_h1 + rr * 256 + ko + i);
    }
    __syncthreads();
    {
      int rr = tid >> 4, ko = (tid & 15) << 4;
#pragma unroll
      for (int i = 0; i < 16; ++i) {
        float v = (float)h1i[rr][ko + i];
        short a0 = bf16_rne(v); float r1 = v - bf16f(a0);
        short a1 = bf16_rne(r1); float r2 = r1 - bf16f(a1);
        phi[rr][ko + i] = a0; pmi[rr][ko + i] = a1; plo[rr][ko + i] = bf16_rne(r2);
      }
    }
    __syncthreads();
    {
      int nt = wv & 1, kh = wv >> 1;
      floatx4 acc = {0.f, 0.f, 0.f, 0.f};
#pragma unroll
      for (int ks = 0; ks < 4; ++ks) {
        int k0 = kh * 128 + ks * 32 + lq * 8;
        short8 a0 = *(short8*)&phi[lm][k0];
        short8 a1 = *(short8*)&pmi[lm][k0];
        short8 a2 = *(short8*)&plo[lm][k0];
        acc = MFMA16(a0, wz2a[ks], acc);
        acc = MFMA16(a0, wz2b[ks], acc);
        acc = MFMA16(a1, wz2a[ks], acc);
        acc = MFMA16(a1, wz2b[ks], acc);
        acc = MFMA16(a0, wz2c[ks], acc);
        acc = MFMA16(a2, wz2a[ks], acc);
      }
#pragma unroll
      for (int i = 0; i < 4; ++i) redbuf[kh * 576 + (lq * 4 + i) * 36 + nt * 16 + lm] = acc[i];
    }
    __syncthreads();
    {
#pragma unroll
      for (int u = 0; u < 2; ++u) {
        int cc = 2 * xc + u;
        float pre = redbuf[xr * 36 + cc] + redbuf[576 + xr * 36 + cc] + (u ? cz2b : cz2a);
        float s = 1.0f / (1.0f + expf(-pre));
        int gcol = cg * 32 + cc;
        if (gcol < 256) {
          float q = floorf((0.875f * s + 0.125f) * 1024.0f);
          int qi = (int)q; qi = qi < 1 ? 1 : (qi > 1024 ? 1024 : qi);
          st_ag(&bc_zq2[xr * 256 + gcol], qi);
        } else {
          int rc = gcol - 256;
          stf_ag(&bc_p2[xr * 256 + rc], s * ((float)h1i[xr][rc] * INV_S));
        }
      }
    }
    __syncthreads();
    if (tid == 0) st_ag(&flagD[cg * 32], 4 * t + 3);
    if (tid < 16) while (ld_ag(&flagD[tid * 32]) < 4 * t + 3) __builtin_amdgcn_s_sleep(2);
    __syncthreads();

    // ================= P4: g2 + h2 update =================
    {
      int rr = tid >> 4, ko = (tid & 15) << 4;
#pragma unroll
      for (int i = 0; i < 16; ++i) {
        float v = ldf_ag(&bc_p2[rr * 256 + ko + i]);
        short a0 = bf16_rne(v);
        phi[rr][ko + i] = a0; plo[rr][ko + i] = bf16_rne(v - bf16f(a0));
      }
    }
    __syncthreads();
    {
      floatx4 acc = {0.f, 0.f, 0.f, 0.f};
#pragma unroll
      for (int ks = 0; ks < 2; ++ks) {
        int k0 = wv * 64 + ks * 32 + lq * 8;
        short8 a0 = *(short8*)&phi[lm][k0];
        short8 a1 = *(short8*)&plo[lm][k0];
        acc = MFMA16(a0, wg2a[ks], acc);
        acc = MFMA16(a1, wg2a[ks], acc);
        acc = MFMA16(a0, wg2b[ks], acc);
      }
#pragma unroll
      for (int i = 0; i < 4; ++i) redbuf[wv * 320 + (lq * 4 + i) * 20 + lm] = acc[i];
    }
    __syncthreads();
    {
      float pre = redbuf[xr * 20 + xc] + redbuf[320 + xr * 20 + xc]
                + redbuf[640 + xr * 20 + xc] + redbuf[960 + xr * 20 + xc] + cg2x;
      float g = tanhf(pre);
      int gc = cg * 16 + xc;
      int q = ld_ag(&bc_zq2[xr * 256 + gc]);
      int hold = h2i[xr][gc];
      float zf = (float)q * (1.0f / 1024.0f);
      int ni = (int)rintf((1.0f - zf) * g * SCALE_F);
      int hnew = (hold >> 10) * q + (((hold & 1023) * q) >> 10) + ni;
      if (t >= lens[xr]) hnew = hold;
      h2i[xr][gc] = hnew;
      st_ag(&bc_h2[xr * 256 + gc], hnew);
      if (layer == 0) g_hs0f[(size_t)(t * 64 + rb0 + xr) * 512 + 256 + gc] = (float)hnew * INV_S;
      if (t == 511) d_out[layer * 32768 + (rb0 + xr) * 512 + 256 + gc] = hnew;
    }
    __syncthreads();
    if (tid == 0) st_ag(&flagD[cg * 32], 4 * t + 4);
    if (tid < 16) while (ld_ag(&flagD[tid * 32]) < 4 * t + 4) __builtin_amdgcn_s_sleep(2);
    __syncthreads();

    cz1a = nz1a; cz1b = nz1b; cg1x = ng1x; cz2a = nz2a; cz2b = nz2b; cg2x = ng2x;
  }
}

// ------------------------------------------------------------------
extern "C" void kernel_launch(void* const* d_in, const int* in_sizes, int n_in,
                              void* d_out, int out_size, void* d_ws, size_t ws_size,
                              hipStream_t stream) {
  const int*   seq     = (const int*)d_in[0];
  const int*   lengths = (const int*)d_in[1];
  const float* emb     = (const float*)d_in[2];
  const float* Wz1     = (const float*)d_in[3];
  const float* bz1     = (const float*)d_in[4];
  const float* Wg1     = (const float*)d_in[5];
  const float* bg1     = (const float*)d_in[6];
  const float* Wz2     = (const float*)d_in[7];
  const float* bz2     = (const float*)d_in[8];
  const float* Wg2     = (const float*)d_in[9];
  const float* bg2     = (const float*)d_in[10];
  int* out = (int*)d_out;
  (void)in_sizes; (void)n_in; (void)out_size; (void)d_ws; (void)ws_size;

  for (int layer = 0; layer < 2; ++layer) {
    prep_kernel<<<3072, 256, 0, stream>>>(Wz1, bz1, Wg1, bg1, Wz2, bz2, Wg2, bg2,
                                          layer, out, layer == 0 ? 1 : 0);
    gemmx_kernel<<<dim3(256, 12), 256, 0, stream>>>(seq, emb, layer == 0 ? 1 : 0);
    scan_kernel<<<64, 256, 0, stream>>>(Wz1, Wg1, Wz2, Wg2, lengths, out, layer);
  }
}